// Round 1
// baseline (890.195 us; speedup 1.0000x reference)
//
#include <hip/hip_runtime.h>
#include <math.h>

#define T_ 2048
#define NH_ 8
#define HD_ 128

// ---------------------------------------------------------------------------
// Generic tiled fp32 GEMM: C[M,N] = act(A[M,K] @ Bw)
// Bw element (k,c) lives at Bw[(c>>cs)*sn + (long)k*sk + (c&cm)]
//   enc layout (NH,DENSE,HD):  cs=7,  cm=127,        sn=131072, sk=128
//   plain row-major (K,N):     cs=30, cm=0x3fffffff, sn=0,      sk=N
// 64x64 tile, BK=16, 256 threads, 4x4 microtile.
// ---------------------------------------------------------------------------
__global__ __launch_bounds__(256) void gemm64(const float* __restrict__ A,
                                              const float* __restrict__ Bw,
                                              float* __restrict__ C,
                                              int M, int N, int Kd,
                                              int cs, int cm, long sn, int sk,
                                              int relu)
{
    __shared__ float As[16][68];   // [k][m], pad 4 keeps float4 alignment
    __shared__ float Bs[16][68];   // [k][n]

    const int tid  = threadIdx.x;
    const int m0   = blockIdx.y * 64;
    const int c0   = blockIdx.x * 64;
    const int arow = tid >> 2;            // 0..63
    const int akq  = (tid & 3) * 4;       // 0,4,8,12
    const int brow = tid >> 4;            // 0..15
    const int bcq  = (tid & 15) * 4;      // 0..60
    const int ty   = tid >> 4;            // 0..15
    const int tx   = tid & 15;            // 0..15

    float acc[4][4] = {};

    for (int k0 = 0; k0 < Kd; k0 += 16) {
        // stage A tile (64 x 16), transposed into As[k][m]
        float4 av = *(const float4*)&A[(long)(m0 + arow) * Kd + k0 + akq];
        As[akq + 0][arow] = av.x;
        As[akq + 1][arow] = av.y;
        As[akq + 2][arow] = av.z;
        As[akq + 3][arow] = av.w;
        // stage B tile (16 x 64)
        {
            int c = c0 + bcq;
            const float* bp = &Bw[(long)(c >> cs) * sn + (long)(k0 + brow) * sk + (c & cm)];
            *(float4*)&Bs[brow][bcq] = *(const float4*)bp;
        }
        __syncthreads();
        #pragma unroll
        for (int kk = 0; kk < 16; ++kk) {
            float4 a4 = *(float4*)&As[kk][ty * 4];
            float4 b4 = *(float4*)&Bs[kk][tx * 4];
            float aa[4] = {a4.x, a4.y, a4.z, a4.w};
            float bb[4] = {b4.x, b4.y, b4.z, b4.w};
            #pragma unroll
            for (int i = 0; i < 4; ++i)
                #pragma unroll
                for (int j = 0; j < 4; ++j)
                    acc[i][j] += aa[i] * bb[j];
        }
        __syncthreads();
    }

    #pragma unroll
    for (int i = 0; i < 4; ++i) {
        float4 o;
        o.x = acc[i][0]; o.y = acc[i][1]; o.z = acc[i][2]; o.w = acc[i][3];
        if (relu) {
            o.x = fmaxf(o.x, 0.f); o.y = fmaxf(o.y, 0.f);
            o.z = fmaxf(o.z, 0.f); o.w = fmaxf(o.w, 0.f);
        }
        *(float4*)&C[(long)(m0 + ty * 4 + i) * N + c0 + tx * 4] = o;
    }
}

// ---------------------------------------------------------------------------
// sig partial sums: per (b, tchunk, j) accumulate full sum and t%8==0 sum
// ---------------------------------------------------------------------------
__global__ void sig_part(const float* __restrict__ Q, float* __restrict__ P)
{
    int j  = blockIdx.x * 256 + threadIdx.x;  // 0..1023
    int tc = blockIdx.y;                      // 0..7
    int b  = blockIdx.z;
    float s = 0.f, s8 = 0.f;
    int t0 = tc * 256;
    for (int t = t0; t < t0 + 256; ++t) {
        float v = Q[((long)(b * T_ + t)) * 1024 + j];
        s += v;
        if ((t & 7) == 0) s8 += v;
    }
    long o = ((long)b * 8 + tc) * 1024 + j;
    P[o * 2]     = s;
    P[o * 2 + 1] = s8;
}

__global__ void sig_fin(const float* __restrict__ P, float* __restrict__ sig)
{
    int j = blockIdx.x * 256 + threadIdx.x;   // 0..1023
    int b = blockIdx.y;
    float s = 0.f, s8 = 0.f;
    for (int tc = 0; tc < 8; ++tc) {
        long o = ((long)b * 8 + tc) * 1024 + j;
        s  += P[o * 2];
        s8 += P[o * 2 + 1];
    }
    sig[b * 1024 + j] = s * (1.0f / 2048.0f) + 0.5f * s8 * (1.0f / 256.0f);
}

// h = gelu(sig @ w1 + b1), exact erf gelu.  grid (2, B), 256 thr
__global__ void mlp1(const float* __restrict__ sig, const float* __restrict__ w1,
                     const float* __restrict__ b1, float* __restrict__ H)
{
    int o = blockIdx.x * 256 + threadIdx.x;   // 0..511
    int b = blockIdx.y;
    float a = 0.f;
    for (int k = 0; k < 1024; ++k)
        a += sig[b * 1024 + k] * w1[(long)k * 512 + o];
    a += b1[o];
    H[b * 512 + o] = 0.5f * a * (1.0f + erff(a * 0.70710678118f));
}

// metric = softplus(base + 0.1*(h @ w2 + b2)).  grid (4, B), 256 thr
__global__ void mlp2(const float* __restrict__ H, const float* __restrict__ w2,
                     const float* __restrict__ b2, const float* __restrict__ base,
                     float* __restrict__ metric)
{
    int c = blockIdx.x * 256 + threadIdx.x;   // 0..1023
    int b = blockIdx.y;
    float a = 0.f;
    for (int k = 0; k < 512; ++k)
        a += H[b * 512 + k] * w2[(long)k * 1024 + c];
    float mv = base[c] + 0.1f * (a + b2[c]);
    metric[b * 1024 + c] = fmaxf(mv, 0.f) + log1pf(expf(-fabsf(mv)));
}

// Mh[h] = U[h] @ V[h]  (128x32)@(32x128).  grid 512, 256 thr
__global__ void hebbmat(const float* __restrict__ U, const float* __restrict__ Vh,
                        float* __restrict__ Mh)
{
    int gid = blockIdx.x * 256 + threadIdx.x;     // 0..131071
    int h = gid >> 14;
    int rem = gid & 16383;
    int f = rem >> 7;
    int e = rem & 127;
    float a = 0.f;
    #pragma unroll
    for (int r = 0; r < 32; ++r)
        a += U[(h * 128 + f) * 32 + r] * Vh[(h * 32 + r) * 128 + e];
    Mh[gid] = a;
}

// ---------------------------------------------------------------------------
// Main context kernel: one wave per (b,t,h).
// distances over 64-window (lane j = window offset), bitonic top-32 by (d,j),
// softmax weights, gather V, hebbian matvec, out = q * context.
// ---------------------------------------------------------------------------
__global__ __launch_bounds__(256) void context_k(
    const float* __restrict__ Q, const float* __restrict__ V,
    const float* __restrict__ metric, const float* __restrict__ Mh,
    float* __restrict__ CT)
{
    __shared__ float qs[4][128], ms[4][128], qu[4][128], wv[4][32];
    __shared__ int   wi[4][32];

    const int w    = threadIdx.x >> 6;
    const int lane = threadIdx.x & 63;
    const int gw   = blockIdx.x * 4 + w;
    const int h    = gw & 7;
    const int bt   = gw >> 3;
    const int t    = bt & (T_ - 1);
    const int b    = bt >> 11;

    const long qbase = ((long)(b * T_ + t) * NH_ + h) * HD_;
    float q0 = Q[qbase + lane], q1 = Q[qbase + 64 + lane];
    float m0 = metric[(b * NH_ + h) * HD_ + lane];
    float m1 = metric[(b * NH_ + h) * HD_ + 64 + lane];
    qs[w][lane] = q0; qs[w][64 + lane] = q1;
    ms[w][lane] = m0; ms[w][64 + lane] = m1;

    // q norm (butterfly -> identical on all lanes)
    float ss = q0 * q0 + q1 * q1;
    #pragma unroll
    for (int s = 32; s; s >>= 1) ss += __shfl_xor(ss, s, 64);
    const float qn  = sqrtf(ss);
    const float inv = 1.0f / fmaxf(qn, 1e-12f);
    qu[w][lane] = q0 * inv; qu[w][64 + lane] = q1 * inv;
    __syncthreads();

    // distance for window offset j = lane (dup idx-0 candidates kept, as in ref)
    int idxj = t - lane; if (idxj < 0) idxj = 0;
    const float* kr = &Q[((long)(b * T_ + idxj) * NH_ + h) * HD_];
    float d2 = 0.f;
    #pragma unroll 4
    for (int e = 0; e < 128; ++e) {
        float diff = kr[e] - qs[w][e];
        d2 += diff * diff * ms[w][e];
    }
    float d = sqrtf(d2 + 1e-8f);
    int jj = lane;

    // bitonic sort ascending by lexicographic (d, jj) — matches lax.top_k ties
    for (int k = 2; k <= 64; k <<= 1) {
        for (int s = k >> 1; s >= 1; s >>= 1) {
            float od = __shfl_xor(d, s, 64);
            int   oj = __shfl_xor(jj, s, 64);
            bool up    = ((lane & k) == 0);
            bool lower = ((lane & s) == 0);
            bool osm   = (od < d) || (od == d && oj < jj);
            if ((lower == up) ? osm : !osm) { d = od; jj = oj; }
        }
    }

    // softmax over the 32 smallest (lanes 0..31)
    float wexp = (lane < 32) ? expf(-d) : 0.f;
    float tot = wexp;
    #pragma unroll
    for (int s = 32; s; s >>= 1) tot += __shfl_xor(tot, s, 64);
    float wn = wexp / (tot + 1e-8f);
    if (lane < 32) {
        wv[w][lane] = wn;
        int ii = t - jj; if (ii < 0) ii = 0;
        wi[w][lane] = ii;
    }
    __syncthreads();

    // context gather: lane owns elements (lane, lane+64)
    float c0 = 0.f, c1 = 0.f;
    #pragma unroll 4
    for (int k = 0; k < 32; ++k) {
        float wk = wv[w][k];
        long vb = ((long)(b * T_ + wi[w][k]) * NH_ + h) * HD_;
        c0 += wk * V[vb + lane];
        c1 += wk * V[vb + 64 + lane];
    }

    // hebbian (gate is wave-uniform)
    if (qn > 0.2f) {
        const float* mh = &Mh[h * 16384];
        float h0 = 0.f, h1 = 0.f;
        #pragma unroll 4
        for (int f = 0; f < 128; ++f) {
            float uf = qu[w][f];
            h0 += uf * mh[f * 128 + lane];
            h1 += uf * mh[f * 128 + 64 + lane];
        }
        c0 += 0.1f * h0; c1 += 0.1f * h1;
    }

    CT[qbase + lane]      = q0 * c0;
    CT[qbase + 64 + lane] = q1 * c1;
}

// ---------------------------------------------------------------------------
extern "C" void kernel_launch(void* const* d_in, const int* in_sizes, int n_in,
                              void* d_out, int out_size, void* d_ws, size_t ws_size,
                              hipStream_t stream)
{
    const float* x     = (const float*)d_in[0];
    const float* enc_q = (const float*)d_in[1];
    const float* enc_v = (const float*)d_in[2];
    const float* w1    = (const float*)d_in[3];
    const float* b1    = (const float*)d_in[4];
    const float* w2    = (const float*)d_in[5];
    const float* b2    = (const float*)d_in[6];
    const float* base  = (const float*)d_in[7];
    const float* hU    = (const float*)d_in[8];
    const float* hV    = (const float*)d_in[9];
    const float* dec   = (const float*)d_in[10];
    float* out = (float*)d_out;
    float* ws  = (float*)d_ws;

    float* Q  = ws;                 // 4096*1024
    float* V  = ws + 4194304;       // 4096*1024
    float* CT = ws + 8388608;       // 4096*1024
    float* Mh = ws + 12582912;      // 8*128*128 = 131072
    float* P  = ws + 12714 * 1000 - 30016; // see below — use explicit offsets instead
    // explicit offsets (floats):
    P         = ws + 12713984;      // 2*8*1024*2 = 32768
    float* sg = ws + 12746752;      // 2*1024
    float* Hh = ws + 12748800;      // 2*512
    float* Me = ws + 12749824;      // 2*1024
    // total = 12751872 floats = ~51 MB

    dim3 gt(16, 64);  // N/64, M/64
    // Q = relu(x @ enc_q), V = relu(x @ enc_v)   (enc layout indexing)
    gemm64<<<gt, 256, 0, stream>>>(x, enc_q, Q, 4096, 1024, 1024, 7, 127, 131072L, 128, 1);
    gemm64<<<gt, 256, 0, stream>>>(x, enc_v, V, 4096, 1024, 1024, 7, 127, 131072L, 128, 1);

    sig_part<<<dim3(4, 8, 2), 256, 0, stream>>>(Q, P);
    sig_fin <<<dim3(4, 2),    256, 0, stream>>>(P, sg);
    mlp1    <<<dim3(2, 2),    256, 0, stream>>>(sg, w1, b1, Hh);
    mlp2    <<<dim3(4, 2),    256, 0, stream>>>(Hh, w2, b2, base, Me);
    hebbmat <<<512,           256, 0, stream>>>(hU, hV, Mh);

    context_k<<<8192, 256, 0, stream>>>(Q, V, Me, Mh, CT);

    // out = CT @ decoder   (plain row-major indexing, no relu)
    gemm64<<<gt, 256, 0, stream>>>(CT, dec, out, 4096, 1024, 1024, 30, 0x3fffffff, 0L, 1024, 0);
}

// Round 2
// 675.637 us; speedup vs baseline: 1.3176x; 1.3176x over previous
//
#include <hip/hip_runtime.h>
#include <math.h>

#define T_ 2048
#define NH_ 8
#define HD_ 128

// ---------------------------------------------------------------------------
// Generic tiled fp32 GEMM: C[M,N] = act(A[M,K] @ Bw)
// Bw element (k,c) lives at Bw[(c>>cs)*sn + (long)k*sk + (c&cm)]
//   enc layout (NH,DENSE,HD):  cs=7,  cm=127,        sn=131072, sk=128
//   plain row-major (K,N):     cs=30, cm=0x3fffffff, sn=0,      sk=N
// 64x64 tile, BK=32 (half the barriers of BK=16), 256 threads, 4x4 microtile.
// ---------------------------------------------------------------------------
__global__ __launch_bounds__(256) void gemm64(const float* __restrict__ A,
                                              const float* __restrict__ Bw,
                                              float* __restrict__ C,
                                              int M, int N, int Kd,
                                              int cs, int cm, long sn, int sk,
                                              int relu)
{
    __shared__ float As[32][68];   // [k][m]
    __shared__ float Bs[32][68];   // [k][n]

    const int tid  = threadIdx.x;
    const int m0   = blockIdx.y * 64;
    const int c0   = blockIdx.x * 64;
    const int arow = tid >> 2;            // 0..63
    const int akq  = (tid & 3) * 8;       // 0,8,16,24
    const int brow = tid >> 3;            // 0..31
    const int bcq  = (tid & 7) * 8;       // 0..56
    const int ty   = tid >> 4;            // 0..15
    const int tx   = tid & 15;            // 0..15

    float acc[4][4] = {};

    for (int k0 = 0; k0 < Kd; k0 += 32) {
        // stage A tile (64 x 32), transposed into As[k][m]
        float4 av0 = *(const float4*)&A[(long)(m0 + arow) * Kd + k0 + akq];
        float4 av1 = *(const float4*)&A[(long)(m0 + arow) * Kd + k0 + akq + 4];
        As[akq + 0][arow] = av0.x;
        As[akq + 1][arow] = av0.y;
        As[akq + 2][arow] = av0.z;
        As[akq + 3][arow] = av0.w;
        As[akq + 4][arow] = av1.x;
        As[akq + 5][arow] = av1.y;
        As[akq + 6][arow] = av1.z;
        As[akq + 7][arow] = av1.w;
        // stage B tile (32 x 64)
        {
            int c = c0 + bcq;
            const float* bp = &Bw[(long)(c >> cs) * sn + (long)(k0 + brow) * sk + (c & cm)];
            *(float4*)&Bs[brow][bcq]     = *(const float4*)bp;
            *(float4*)&Bs[brow][bcq + 4] = *(const float4*)(bp + 4);
        }
        __syncthreads();
        #pragma unroll
        for (int kk = 0; kk < 32; ++kk) {
            float4 a4 = *(float4*)&As[kk][ty * 4];
            float4 b4 = *(float4*)&Bs[kk][tx * 4];
            float aa[4] = {a4.x, a4.y, a4.z, a4.w};
            float bb[4] = {b4.x, b4.y, b4.z, b4.w};
            #pragma unroll
            for (int i = 0; i < 4; ++i)
                #pragma unroll
                for (int j = 0; j < 4; ++j)
                    acc[i][j] += aa[i] * bb[j];
        }
        __syncthreads();
    }

    #pragma unroll
    for (int i = 0; i < 4; ++i) {
        float4 o;
        o.x = acc[i][0]; o.y = acc[i][1]; o.z = acc[i][2]; o.w = acc[i][3];
        if (relu) {
            o.x = fmaxf(o.x, 0.f); o.y = fmaxf(o.y, 0.f);
            o.z = fmaxf(o.z, 0.f); o.w = fmaxf(o.w, 0.f);
        }
        *(float4*)&C[(long)(m0 + ty * 4 + i) * N + c0 + tx * 4] = o;
    }
}

// ---------------------------------------------------------------------------
// sig partial sums: per (b, tchunk, j) accumulate full sum and t%8==0 sum
// ---------------------------------------------------------------------------
__global__ void sig_part(const float* __restrict__ Q, float* __restrict__ P)
{
    int j  = blockIdx.x * 256 + threadIdx.x;  // 0..1023
    int tc = blockIdx.y;                      // 0..7
    int b  = blockIdx.z;
    float s = 0.f, s8 = 0.f;
    int t0 = tc * 256;
    for (int t = t0; t < t0 + 256; ++t) {
        float v = Q[((long)(b * T_ + t)) * 1024 + j];
        s += v;
        if ((t & 7) == 0) s8 += v;
    }
    long o = ((long)b * 8 + tc) * 1024 + j;
    P[o * 2]     = s;
    P[o * 2 + 1] = s8;
}

__global__ void sig_fin(const float* __restrict__ P, float* __restrict__ sig)
{
    int j = blockIdx.x * 256 + threadIdx.x;   // 0..1023
    int b = blockIdx.y;
    float s = 0.f, s8 = 0.f;
    for (int tc = 0; tc < 8; ++tc) {
        long o = ((long)b * 8 + tc) * 1024 + j;
        s  += P[o * 2];
        s8 += P[o * 2 + 1];
    }
    sig[b * 1024 + j] = s * (1.0f / 2048.0f) + 0.5f * s8 * (1.0f / 256.0f);
}

// h = gelu(sig @ w1 + b1), exact erf gelu.  grid (2, B), 256 thr
__global__ void mlp1(const float* __restrict__ sig, const float* __restrict__ w1,
                     const float* __restrict__ b1, float* __restrict__ H)
{
    int o = blockIdx.x * 256 + threadIdx.x;   // 0..511
    int b = blockIdx.y;
    float a = 0.f;
    for (int k = 0; k < 1024; ++k)
        a += sig[b * 1024 + k] * w1[(long)k * 512 + o];
    a += b1[o];
    H[b * 512 + o] = 0.5f * a * (1.0f + erff(a * 0.70710678118f));
}

// metric = softplus(base + 0.1*(h @ w2 + b2)).  grid (4, B), 256 thr
__global__ void mlp2(const float* __restrict__ H, const float* __restrict__ w2,
                     const float* __restrict__ b2, const float* __restrict__ base,
                     float* __restrict__ metric)
{
    int c = blockIdx.x * 256 + threadIdx.x;   // 0..1023
    int b = blockIdx.y;
    float a = 0.f;
    for (int k = 0; k < 512; ++k)
        a += H[b * 512 + k] * w2[(long)k * 1024 + c];
    float mv = base[c] + 0.1f * (a + b2[c]);
    metric[b * 1024 + c] = fmaxf(mv, 0.f) + log1pf(expf(-fabsf(mv)));
}

// Mh[h] = U[h] @ V[h]  (128x32)@(32x128).  grid 512, 256 thr
__global__ void hebbmat(const float* __restrict__ U, const float* __restrict__ Vh,
                        float* __restrict__ Mh)
{
    int gid = blockIdx.x * 256 + threadIdx.x;     // 0..131071
    int h = gid >> 14;
    int rem = gid & 16383;
    int f = rem >> 7;
    int e = rem & 127;
    float a = 0.f;
    #pragma unroll
    for (int r = 0; r < 32; ++r)
        a += U[(h * 128 + f) * 32 + r] * Vh[(h * 32 + r) * 128 + e];
    Mh[gid] = a;
}

// ---------------------------------------------------------------------------
// Main context kernel v2: one wave per (b,t,h), waves fully independent
// (no __syncthreads — all LDS is wave-private, indexed by w).
// Distance phase: lanes span elements (float4/lane, 32 lanes = HD), loop
// window offsets 2 at a time (half-wave each) -> all global loads coalesced
// (2 x 512B contiguous per instruction vs 64 scattered lines before).
// ---------------------------------------------------------------------------
__global__ __launch_bounds__(256) void context_k(
    const float* __restrict__ Q, const float* __restrict__ V,
    const float* __restrict__ metric, const float* __restrict__ Mh,
    float* __restrict__ CT)
{
    __shared__ float qu[4][128], dq[4][64], wv[4][32];
    __shared__ int   wi[4][32];

    const int w    = threadIdx.x >> 6;
    const int lane = threadIdx.x & 63;
    const int gw   = blockIdx.x * 4 + w;
    const int h    = gw & 7;
    const int bt   = gw >> 3;
    const int t    = bt & (T_ - 1);
    const int b    = bt >> 11;

    const long qbase = ((long)(b * T_ + t) * NH_ + h) * HD_;

    // ---- distance phase: lane covers 4 elements, half-wave per j ----
    const int e4     = (lane & 31) * 4;
    const int jhalf  = lane >> 5;
    const float4 qv  = *(const float4*)&Q[qbase + e4];
    const float4 mv  = *(const float4*)&metric[(long)(b * NH_ + h) * HD_ + e4];

    #pragma unroll 4
    for (int it = 0; it < 32; ++it) {
        int j = 2 * it + jhalf;
        int r = t - j; if (r < 0) r = 0;
        const float4 kv = *(const float4*)&Q[((long)(b * T_ + r) * NH_ + h) * HD_ + e4];
        float dx = kv.x - qv.x;
        float dy = kv.y - qv.y;
        float dz = kv.z - qv.z;
        float de = kv.w - qv.w;
        float s = mv.x * dx * dx + mv.y * dy * dy + mv.z * dz * dz + mv.w * de * de;
        #pragma unroll
        for (int m = 16; m; m >>= 1) s += __shfl_xor(s, m, 64);  // reduce within 32-half
        if ((lane & 31) == 0) dq[w][j] = s;
    }

    // ---- q norm + unit q (lane-layout: lane owns elements lane, lane+64) ----
    float q0 = Q[qbase + lane], q1 = Q[qbase + 64 + lane];
    float ss = q0 * q0 + q1 * q1;
    #pragma unroll
    for (int s = 32; s; s >>= 1) ss += __shfl_xor(ss, s, 64);
    const float qn  = sqrtf(ss);
    const float inv = 1.0f / fmaxf(qn, 1e-12f);
    qu[w][lane] = q0 * inv; qu[w][64 + lane] = q1 * inv;

    // ---- pick up d for this lane's window offset ----
    float d = sqrtf(dq[w][lane] + 1e-8f);
    int jj = lane;

    // bitonic sort ascending by lexicographic (d, jj) — matches lax.top_k ties
    for (int k = 2; k <= 64; k <<= 1) {
        for (int s = k >> 1; s >= 1; s >>= 1) {
            float od = __shfl_xor(d, s, 64);
            int   oj = __shfl_xor(jj, s, 64);
            bool up    = ((lane & k) == 0);
            bool lower = ((lane & s) == 0);
            bool osm   = (od < d) || (od == d && oj < jj);
            if ((lower == up) ? osm : !osm) { d = od; jj = oj; }
        }
    }

    // softmax over the 32 smallest (lanes 0..31)
    float wexp = (lane < 32) ? expf(-d) : 0.f;
    float tot = wexp;
    #pragma unroll
    for (int s = 32; s; s >>= 1) tot += __shfl_xor(tot, s, 64);
    float wn = wexp / (tot + 1e-8f);
    if (lane < 32) {
        wv[w][lane] = wn;
        int ii = t - jj; if (ii < 0) ii = 0;
        wi[w][lane] = ii;
    }

    // ---- context gather: lane owns elements (lane, lane+64) ----
    float c0 = 0.f, c1 = 0.f;
    #pragma unroll 4
    for (int k = 0; k < 32; ++k) {
        float wk = wv[w][k];
        long vb = ((long)(b * T_ + wi[w][k]) * NH_ + h) * HD_;
        c0 += wk * V[vb + lane];
        c1 += wk * V[vb + 64 + lane];
    }

    // ---- hebbian (gate is wave-uniform) ----
    if (qn > 0.2f) {
        const float* mh = &Mh[h * 16384];
        float h0 = 0.f, h1 = 0.f;
        #pragma unroll 4
        for (int f = 0; f < 128; ++f) {
            float uf = qu[w][f];
            h0 += uf * mh[f * 128 + lane];
            h1 += uf * mh[f * 128 + 64 + lane];
        }
        c0 += 0.1f * h0; c1 += 0.1f * h1;
    }

    CT[qbase + lane]      = q0 * c0;
    CT[qbase + 64 + lane] = q1 * c1;
}

// ---------------------------------------------------------------------------
extern "C" void kernel_launch(void* const* d_in, const int* in_sizes, int n_in,
                              void* d_out, int out_size, void* d_ws, size_t ws_size,
                              hipStream_t stream)
{
    const float* x     = (const float*)d_in[0];
    const float* enc_q = (const float*)d_in[1];
    const float* enc_v = (const float*)d_in[2];
    const float* w1    = (const float*)d_in[3];
    const float* b1    = (const float*)d_in[4];
    const float* w2    = (const float*)d_in[5];
    const float* b2    = (const float*)d_in[6];
    const float* base  = (const float*)d_in[7];
    const float* hU    = (const float*)d_in[8];
    const float* hV    = (const float*)d_in[9];
    const float* dec   = (const float*)d_in[10];
    float* out = (float*)d_out;
    float* ws  = (float*)d_ws;

    float* Q  = ws;                 // 4096*1024
    float* V  = ws + 4194304;       // 4096*1024
    float* CT = ws + 8388608;       // 4096*1024
    float* Mh = ws + 12582912;      // 8*128*128 = 131072
    float* P  = ws + 12713984;      // 2*8*1024*2 = 32768
    float* sg = ws + 12746752;      // 2*1024
    float* Hh = ws + 12748800;      // 2*512
    float* Me = ws + 12749824;      // 2*1024

    dim3 gt(16, 64);  // N/64, M/64
    // Q = relu(x @ enc_q), V = relu(x @ enc_v)   (enc layout indexing)
    gemm64<<<gt, 256, 0, stream>>>(x, enc_q, Q, 4096, 1024, 1024, 7, 127, 131072L, 128, 1);
    gemm64<<<gt, 256, 0, stream>>>(x, enc_v, V, 4096, 1024, 1024, 7, 127, 131072L, 128, 1);

    sig_part<<<dim3(4, 8, 2), 256, 0, stream>>>(Q, P);
    sig_fin <<<dim3(4, 2),    256, 0, stream>>>(P, sg);
    mlp1    <<<dim3(2, 2),    256, 0, stream>>>(sg, w1, b1, Hh);
    mlp2    <<<dim3(4, 2),    256, 0, stream>>>(Hh, w2, b2, base, Me);
    hebbmat <<<512,           256, 0, stream>>>(hU, hV, Mh);

    context_k<<<8192, 256, 0, stream>>>(Q, V, Me, Mh, CT);

    // out = CT @ decoder   (plain row-major indexing, no relu)
    gemm64<<<gt, 256, 0, stream>>>(CT, dec, out, 4096, 1024, 1024, 30, 0x3fffffff, 0L, 1024, 0);
}

// Round 3
// 608.350 us; speedup vs baseline: 1.4633x; 1.1106x over previous
//
#include <hip/hip_runtime.h>
#include <math.h>

#define T_ 2048
#define NH_ 8
#define HD_ 128

typedef unsigned short u16;
typedef short bf16x8 __attribute__((ext_vector_type(8)));
typedef float f32x4 __attribute__((ext_vector_type(4)));

// ---------------------------------------------------------------------------
// fp32 -> (hi, lo) bf16 split, round-to-nearest-even both halves.
// a ~= hi + lo with relative error ~2^-17.
// ---------------------------------------------------------------------------
__device__ __forceinline__ void split1(float f, u16& h, u16& l)
{
    unsigned u = __float_as_uint(f);
    unsigned hr = (u + 0x7FFFu + ((u >> 16) & 1u)) >> 16;
    h = (u16)hr;
    float fh = __uint_as_float(hr << 16);
    float r = f - fh;                       // exact
    unsigned u2 = __float_as_uint(r);
    l = (u16)((u2 + 0x7FFFu + ((u2 >> 16) & 1u)) >> 16);
}

// elementwise split of x: [n] fp32 -> hi/lo bf16.  n multiple of 1024.
__global__ __launch_bounds__(256) void cvt_split(const float* __restrict__ in,
                                                 u16* __restrict__ hi,
                                                 u16* __restrict__ lo, int n)
{
    int i = (blockIdx.x * 256 + threadIdx.x) * 4;
    if (i >= n) return;
    float4 v = *(const float4*)&in[i];
    u16 h0, l0, h1, l1, h2, l2, h3, l3;
    split1(v.x, h0, l0); split1(v.y, h1, l1);
    split1(v.z, h2, l2); split1(v.w, h3, l3);
    ushort4 hv = {h0, h1, h2, h3}, lv = {l0, l1, l2, l3};
    *(ushort4*)&hi[i] = hv;
    *(ushort4*)&lo[i] = lv;
}

// ---------------------------------------------------------------------------
// Weight convert + transpose: Bw element (k,c) at (c>>cs)*sn + k*sk + (c&cm)
// -> WT_hi/WT_lo [N=1024][K] bf16 (k contiguous).  grid (Kd/32, 32), 256 thr.
// ---------------------------------------------------------------------------
__global__ __launch_bounds__(256) void cvt_wT(const float* __restrict__ Bw,
                                              u16* __restrict__ WTh,
                                              u16* __restrict__ WTl,
                                              int Kd, int cs, int cm, long sn, int sk)
{
    __shared__ u16 tH[32][33], tL[32][33];
    const int tid = threadIdx.x;
    const int tx = tid & 31, ty = tid >> 5;      // ty 0..7
    const int k0 = blockIdx.x * 32, c0 = blockIdx.y * 32;
    #pragma unroll
    for (int r = 0; r < 4; ++r) {
        int k = k0 + ty * 4 + r;
        int c = c0 + tx;
        float v = Bw[(long)(c >> cs) * sn + (long)k * sk + (c & cm)];
        u16 h, l; split1(v, h, l);
        tH[ty * 4 + r][tx] = h;
        tL[ty * 4 + r][tx] = l;
    }
    __syncthreads();
    #pragma unroll
    for (int r = 0; r < 4; ++r) {
        int n = c0 + ty * 4 + r;
        WTh[(long)n * Kd + k0 + tx] = tH[tx][ty * 4 + r];
        WTl[(long)n * Kd + k0 + tx] = tL[tx][ty * 4 + r];
    }
}

// ---------------------------------------------------------------------------
// Split-bf16 MFMA GEMM: C[M,N] = act((Ah+Al) @ (Bh+Bl)^T-layout)
//   A hi/lo: [M][K] bf16 row-major.  B hi/lo: [N][K] bf16 (pre-transposed).
//   C fp32 [M][N].  Tile 128x128, BK=32, 256 thr (4 waves, 64x64 each).
// LDS: fragment-contiguous [kq][row][8] (unpadded -> global_load_lds-safe,
// lane-linear ds_read_b128 -> conflict-free).
// mfma_f32_16x16x32_bf16: A[m=lane&15][k=(lane>>4)*8+j], B[k][n=lane&15],
// C/D: col=lane&15, row=(lane>>4)*4+reg   [verified layouts, guide §3]
// ---------------------------------------------------------------------------
__global__ __launch_bounds__(256) void gemm_mfma(
    const u16* __restrict__ Ah, const u16* __restrict__ Al,
    const u16* __restrict__ Bh, const u16* __restrict__ Bl,
    float* __restrict__ C, int M, int N, int Kd, int relu)
{
    __shared__ u16 sAh[4][128][8], sAl[4][128][8], sBh[4][128][8], sBl[4][128][8];

    const int tid  = threadIdx.x;
    const int w    = tid >> 6;
    const int lane = tid & 63;
    const int m0   = blockIdx.y * 128, n0 = blockIdx.x * 128;
    const int mw   = (w & 1) * 64, nw = (w >> 1) * 64;
    const int mr   = lane & 15, quad = lane >> 4;

    // wave w stages tile w: 0->Ah, 1->Al, 2->Bh, 3->Bl
    const u16* P = (w == 0) ? Ah : (w == 1) ? Al : (w == 2) ? Bh : Bl;
    u16* D = (w == 0) ? &sAh[0][0][0] : (w == 1) ? &sAl[0][0][0]
           : (w == 2) ? &sBh[0][0][0] : &sBl[0][0][0];
    const int rbase = (w < 2) ? m0 : n0;

    f32x4 acc[4][4] = {};

    for (int k0 = 0; k0 < Kd; k0 += 32) {
        #pragma unroll
        for (int q = 0; q < 8; ++q) {
            int kq = q >> 1, half = q & 1;
            const u16* gp = P + (long)(rbase + half * 64 + lane) * Kd + k0 + kq * 8;
            u16* lp = D + kq * 1024 + half * 512;   // wave-uniform base; HW adds lane*16
            __builtin_amdgcn_global_load_lds(
                (const __attribute__((address_space(1))) unsigned int*)gp,
                (__attribute__((address_space(3))) unsigned int*)lp, 16, 0, 0);
        }
        __syncthreads();

        bf16x8 fah[4], fal[4], fbh[4], fbl[4];
        #pragma unroll
        for (int i = 0; i < 4; ++i) {
            fah[i] = *(const bf16x8*)&sAh[quad][mw + i * 16 + mr][0];
            fal[i] = *(const bf16x8*)&sAl[quad][mw + i * 16 + mr][0];
            fbh[i] = *(const bf16x8*)&sBh[quad][nw + i * 16 + mr][0];
            fbl[i] = *(const bf16x8*)&sBl[quad][nw + i * 16 + mr][0];
        }
        #pragma unroll
        for (int i = 0; i < 4; ++i)
            #pragma unroll
            for (int j = 0; j < 4; ++j) {
                acc[i][j] = __builtin_amdgcn_mfma_f32_16x16x32_bf16(fah[i], fbh[j], acc[i][j], 0, 0, 0);
                acc[i][j] = __builtin_amdgcn_mfma_f32_16x16x32_bf16(fah[i], fbl[j], acc[i][j], 0, 0, 0);
                acc[i][j] = __builtin_amdgcn_mfma_f32_16x16x32_bf16(fal[i], fbh[j], acc[i][j], 0, 0, 0);
            }
        __syncthreads();
    }

    #pragma unroll
    for (int i = 0; i < 4; ++i)
        #pragma unroll
        for (int j = 0; j < 4; ++j)
            #pragma unroll
            for (int r = 0; r < 4; ++r) {
                int row = m0 + mw + i * 16 + quad * 4 + r;
                int col = n0 + nw + j * 16 + mr;
                float v = acc[i][j][r];
                if (relu) v = fmaxf(v, 0.f);
                C[(long)row * N + col] = v;
            }
}

// ---------------------------------------------------------------------------
// sig partial sums
// ---------------------------------------------------------------------------
__global__ void sig_part(const float* __restrict__ Q, float* __restrict__ P)
{
    int j  = blockIdx.x * 256 + threadIdx.x;
    int tc = blockIdx.y;
    int b  = blockIdx.z;
    float s = 0.f, s8 = 0.f;
    int t0 = tc * 256;
    for (int t = t0; t < t0 + 256; ++t) {
        float v = Q[((long)(b * T_ + t)) * 1024 + j];
        s += v;
        if ((t & 7) == 0) s8 += v;
    }
    long o = ((long)b * 8 + tc) * 1024 + j;
    P[o * 2]     = s;
    P[o * 2 + 1] = s8;
}

__global__ void sig_fin(const float* __restrict__ P, float* __restrict__ sig)
{
    int j = blockIdx.x * 256 + threadIdx.x;
    int b = blockIdx.y;
    float s = 0.f, s8 = 0.f;
    for (int tc = 0; tc < 8; ++tc) {
        long o = ((long)b * 8 + tc) * 1024 + j;
        s  += P[o * 2];
        s8 += P[o * 2 + 1];
    }
    sig[b * 1024 + j] = s * (1.0f / 2048.0f) + 0.5f * s8 * (1.0f / 256.0f);
}

__global__ void mlp1(const float* __restrict__ sig, const float* __restrict__ w1,
                     const float* __restrict__ b1, float* __restrict__ H)
{
    int o = blockIdx.x * 256 + threadIdx.x;
    int b = blockIdx.y;
    float a = 0.f;
    for (int k = 0; k < 1024; ++k)
        a += sig[b * 1024 + k] * w1[(long)k * 512 + o];
    a += b1[o];
    H[b * 512 + o] = 0.5f * a * (1.0f + erff(a * 0.70710678118f));
}

__global__ void mlp2(const float* __restrict__ H, const float* __restrict__ w2,
                     const float* __restrict__ b2, const float* __restrict__ base,
                     float* __restrict__ metric)
{
    int c = blockIdx.x * 256 + threadIdx.x;
    int b = blockIdx.y;
    float a = 0.f;
    for (int k = 0; k < 512; ++k)
        a += H[b * 512 + k] * w2[(long)k * 1024 + c];
    float mv = base[c] + 0.1f * (a + b2[c]);
    metric[b * 1024 + c] = fmaxf(mv, 0.f) + log1pf(expf(-fabsf(mv)));
}

__global__ void hebbmat(const float* __restrict__ U, const float* __restrict__ Vh,
                        float* __restrict__ Mh)
{
    int gid = blockIdx.x * 256 + threadIdx.x;
    int h = gid >> 14;
    int rem = gid & 16383;
    int f = rem >> 7;
    int e = rem & 127;
    float a = 0.f;
    #pragma unroll
    for (int r = 0; r < 32; ++r)
        a += U[(h * 128 + f) * 32 + r] * Vh[(h * 32 + r) * 128 + e];
    Mh[gid] = a;
}

// ---------------------------------------------------------------------------
// Context kernel (same math as round 2); epilogue emits CT as hi/lo bf16
// so the decoder GEMM consumes it directly.
// ---------------------------------------------------------------------------
__global__ __launch_bounds__(256) void context_k(
    const float* __restrict__ Q, const float* __restrict__ V,
    const float* __restrict__ metric, const float* __restrict__ Mh,
    u16* __restrict__ CTh, u16* __restrict__ CTl)
{
    __shared__ float qu[4][128], dq[4][64], wv[4][32];
    __shared__ int   wi[4][32];

    const int w    = threadIdx.x >> 6;
    const int lane = threadIdx.x & 63;
    const int gw   = blockIdx.x * 4 + w;
    const int h    = gw & 7;
    const int bt   = gw >> 3;
    const int t    = bt & (T_ - 1);
    const int b    = bt >> 11;

    const long qbase = ((long)(b * T_ + t) * NH_ + h) * HD_;

    const int e4     = (lane & 31) * 4;
    const int jhalf  = lane >> 5;
    const float4 qv  = *(const float4*)&Q[qbase + e4];
    const float4 mv  = *(const float4*)&metric[(long)(b * NH_ + h) * HD_ + e4];

    #pragma unroll 4
    for (int it = 0; it < 32; ++it) {
        int j = 2 * it + jhalf;
        int r = t - j; if (r < 0) r = 0;
        const float4 kv = *(const float4*)&Q[((long)(b * T_ + r) * NH_ + h) * HD_ + e4];
        float dx = kv.x - qv.x;
        float dy = kv.y - qv.y;
        float dz = kv.z - qv.z;
        float de = kv.w - qv.w;
        float s = mv.x * dx * dx + mv.y * dy * dy + mv.z * dz * dz + mv.w * de * de;
        #pragma unroll
        for (int m = 16; m; m >>= 1) s += __shfl_xor(s, m, 64);
        if ((lane & 31) == 0) dq[w][j] = s;
    }

    float q0 = Q[qbase + lane], q1 = Q[qbase + 64 + lane];
    float ss = q0 * q0 + q1 * q1;
    #pragma unroll
    for (int s = 32; s; s >>= 1) ss += __shfl_xor(ss, s, 64);
    const float qn  = sqrtf(ss);
    const float inv = 1.0f / fmaxf(qn, 1e-12f);
    qu[w][lane] = q0 * inv; qu[w][64 + lane] = q1 * inv;

    float d = sqrtf(dq[w][lane] + 1e-8f);
    int jj = lane;

    for (int k = 2; k <= 64; k <<= 1) {
        for (int s = k >> 1; s >= 1; s >>= 1) {
            float od = __shfl_xor(d, s, 64);
            int   oj = __shfl_xor(jj, s, 64);
            bool up    = ((lane & k) == 0);
            bool lower = ((lane & s) == 0);
            bool osm   = (od < d) || (od == d && oj < jj);
            if ((lower == up) ? osm : !osm) { d = od; jj = oj; }
        }
    }

    float wexp = (lane < 32) ? expf(-d) : 0.f;
    float tot = wexp;
    #pragma unroll
    for (int s = 32; s; s >>= 1) tot += __shfl_xor(tot, s, 64);
    float wn = wexp / (tot + 1e-8f);
    if (lane < 32) {
        wv[w][lane] = wn;
        int ii = t - jj; if (ii < 0) ii = 0;
        wi[w][lane] = ii;
    }

    float c0 = 0.f, c1 = 0.f;
    #pragma unroll 4
    for (int k = 0; k < 32; ++k) {
        float wk = wv[w][k];
        long vb = ((long)(b * T_ + wi[w][k]) * NH_ + h) * HD_;
        c0 += wk * V[vb + lane];
        c1 += wk * V[vb + 64 + lane];
    }

    if (qn > 0.2f) {
        const float* mh = &Mh[h * 16384];
        float h0 = 0.f, h1 = 0.f;
        #pragma unroll 4
        for (int f = 0; f < 128; ++f) {
            float uf = qu[w][f];
            h0 += uf * mh[f * 128 + lane];
            h1 += uf * mh[f * 128 + 64 + lane];
        }
        c0 += 0.1f * h0; c1 += 0.1f * h1;
    }

    u16 hh, ll;
    split1(q0 * c0, hh, ll);
    CTh[qbase + lane] = hh; CTl[qbase + lane] = ll;
    split1(q1 * c1, hh, ll);
    CTh[qbase + 64 + lane] = hh; CTl[qbase + 64 + lane] = ll;
}

// ---------------------------------------------------------------------------
extern "C" void kernel_launch(void* const* d_in, const int* in_sizes, int n_in,
                              void* d_out, int out_size, void* d_ws, size_t ws_size,
                              hipStream_t stream)
{
    const float* x     = (const float*)d_in[0];
    const float* enc_q = (const float*)d_in[1];
    const float* enc_v = (const float*)d_in[2];
    const float* w1    = (const float*)d_in[3];
    const float* b1    = (const float*)d_in[4];
    const float* w2    = (const float*)d_in[5];
    const float* b2    = (const float*)d_in[6];
    const float* base  = (const float*)d_in[7];
    const float* hU    = (const float*)d_in[8];
    const float* hV    = (const float*)d_in[9];
    const float* dec   = (const float*)d_in[10];
    float* out = (float*)d_out;
    float* ws  = (float*)d_ws;

    // ws layout (float words), peak 12.75M floats = 51 MB (same as round 2):
    float* Q   = ws;                        // [0, 4194304)
    float* V   = ws + 4194304;              // [4194304, 8388608); later: wdT hi/lo
    // region C [8388608, 12582912): first wT hi/lo (enc_q then enc_v), then CTh/CTl
    u16* wTh   = (u16*)(ws + 8388608);      // 1024*1024 u16
    u16* wTl   = (u16*)(ws + 8912896);
    u16* CTh   = (u16*)(ws + 8388608);      // 4096*1024 u16 (after wT dead)
    u16* CTl   = (u16*)(ws + 10485760);
    float* Mh  = ws + 12582912;
    float* P   = ws + 12713984;
    float* sg  = ws + 12746752;
    float* Hh  = ws + 12748800;
    float* Me  = ws + 12749824;
    u16* wdTh  = (u16*)(ws + 4194304);      // V region, after context_k
    u16* wdTl  = (u16*)(ws + 4718592);
    // x hi/lo live in d_out (dead before final GEMM writes it)
    u16* xh    = (u16*)d_out;               // 4096*1024 u16
    u16* xl    = xh + 4194304;

    dim3 gg(8, 32);   // N/128, M/128
    dim3 gw32(32, 32);

    cvt_split<<<4096, 256, 0, stream>>>(x, xh, xl, 4194304);

    // Q = relu((x) @ enc_q)
    cvt_wT<<<gw32, 256, 0, stream>>>(enc_q, wTh, wTl, 1024, 7, 127, 131072L, 128);
    gemm_mfma<<<gg, 256, 0, stream>>>(xh, xl, wTh, wTl, Q, 4096, 1024, 1024, 1);
    // V = relu((x) @ enc_v)
    cvt_wT<<<gw32, 256, 0, stream>>>(enc_v, wTh, wTl, 1024, 7, 127, 131072L, 128);
    gemm_mfma<<<gg, 256, 0, stream>>>(xh, xl, wTh, wTl, V, 4096, 1024, 1024, 1);

    sig_part<<<dim3(4, 8, 2), 256, 0, stream>>>(Q, P);
    sig_fin <<<dim3(4, 2),    256, 0, stream>>>(P, sg);
    mlp1    <<<dim3(2, 2),    256, 0, stream>>>(sg, w1, b1, Hh);
    mlp2    <<<dim3(4, 2),    256, 0, stream>>>(Hh, w2, b2, base, Me);
    hebbmat <<<512,           256, 0, stream>>>(hU, hV, Mh);

    context_k<<<8192, 256, 0, stream>>>(Q, V, Me, Mh, CTh, CTl);

    // out = (CT) @ decoder
    cvt_wT<<<gw32, 256, 0, stream>>>(dec, wdTh, wdTl, 1024, 30, 0x3fffffff, 0L, 1024);
    gemm_mfma<<<gg, 256, 0, stream>>>(CTh, CTl, wdTh, wdTl, out, 4096, 1024, 1024, 0);
}

// Round 4
// 562.052 us; speedup vs baseline: 1.5838x; 1.0824x over previous
//
#include <hip/hip_runtime.h>
#include <math.h>

#define T_ 2048
#define NH_ 8
#define HD_ 128

typedef unsigned short u16;
typedef short bf16x8 __attribute__((ext_vector_type(8)));
typedef float f32x4 __attribute__((ext_vector_type(4)));

__device__ __forceinline__ u16 f2bf(float f)
{
    unsigned u = __float_as_uint(f);
    return (u16)((u + 0x7FFFu + ((u >> 16) & 1u)) >> 16);
}
__device__ __forceinline__ float bf2f(u16 h)
{
    return __uint_as_float(((unsigned)h) << 16);
}
// fp32 -> (hi, lo) bf16 split; a ~= hi + lo, rel err ~2^-17
__device__ __forceinline__ void split1(float f, u16& h, u16& l)
{
    h = f2bf(f);
    l = f2bf(f - bf2f(h));
}

// elementwise split of x: [n] fp32 -> hi/lo bf16
__global__ __launch_bounds__(256) void cvt_split(const float* __restrict__ in,
                                                 u16* __restrict__ hi,
                                                 u16* __restrict__ lo, int n)
{
    int i = (blockIdx.x * 256 + threadIdx.x) * 4;
    if (i >= n) return;
    float4 v = *(const float4*)&in[i];
    u16 h0, l0, h1, l1, h2, l2, h3, l3;
    split1(v.x, h0, l0); split1(v.y, h1, l1);
    split1(v.z, h2, l2); split1(v.w, h3, l3);
    ushort4 hv = {h0, h1, h2, h3}, lv = {l0, l1, l2, l3};
    *(ushort4*)&hi[i] = hv;
    *(ushort4*)&lo[i] = lv;
}

// ---------------------------------------------------------------------------
// Weight convert + transpose: Bw element (k,c) at (c>>cs)*sn + k*sk + (c&cm)
// -> WT_hi/WT_lo [n][Kd] bf16 (k contiguous).  grid (Kd/32, Ncols/32), 256 thr.
// ---------------------------------------------------------------------------
__global__ __launch_bounds__(256) void cvt_wT(const float* __restrict__ Bw,
                                              u16* __restrict__ WTh,
                                              u16* __restrict__ WTl,
                                              int Kd, int cs, int cm, long sn, int sk)
{
    __shared__ u16 tH[32][33], tL[32][33];
    const int tid = threadIdx.x;
    const int tx = tid & 31, ty = tid >> 5;
    const int k0 = blockIdx.x * 32, c0 = blockIdx.y * 32;
    #pragma unroll
    for (int r = 0; r < 4; ++r) {
        int k = k0 + ty * 4 + r;
        int c = c0 + tx;
        float v = Bw[(long)(c >> cs) * sn + (long)k * sk + (c & cm)];
        u16 h, l; split1(v, h, l);
        tH[ty * 4 + r][tx] = h;
        tL[ty * 4 + r][tx] = l;
    }
    __syncthreads();
    #pragma unroll
    for (int r = 0; r < 4; ++r) {
        int n = c0 + ty * 4 + r;
        WTh[(long)n * Kd + k0 + tx] = tH[tx][ty * 4 + r];
        WTl[(long)n * Kd + k0 + tx] = tL[tx][ty * 4 + r];
    }
}

// ---------------------------------------------------------------------------
// Split-bf16 MFMA GEMM: C[M,N] = act((Ah+Al) @ (Bh+Bl))
//   A hi/lo: [M][Kd] bf16.  B hi/lo: [N][Kd] bf16 (pre-transposed).
// Tile 128x64 (M x N), BK=32, 256 thr / 4 waves (each 32x64).
// 24 KB LDS -> ~4 blocks/CU; QV grid 1024 blocks (4/CU).
// ---------------------------------------------------------------------------
__global__ __launch_bounds__(256) void gemm_mfma(
    const u16* __restrict__ Ah, const u16* __restrict__ Al,
    const u16* __restrict__ Bh, const u16* __restrict__ Bl,
    float* __restrict__ C, int M, int N, int Kd, int relu)
{
    __shared__ __align__(16) u16 sAh[4][128][8], sAl[4][128][8];
    __shared__ __align__(16) u16 sBh[4][64][8],  sBl[4][64][8];

    const int tid  = threadIdx.x;
    const int w    = tid >> 6;
    const int lane = tid & 63;
    const int m0   = blockIdx.y * 128, n0 = blockIdx.x * 64;
    const int mw   = w * 32;
    const int mr   = lane & 15, quad = lane >> 4;

    f32x4 acc[2][4] = {};

    for (int k0 = 0; k0 < Kd; k0 += 32) {
        // stage 24 KB as 24 x 1KB chunks; wave w stages chunks 6w..6w+5
        #pragma unroll
        for (int u = 0; u < 6; ++u) {
            int c = w * 6 + u;
            const u16* src; u16* dst; long gofs;
            if (c < 16) {
                int cc = c & 7;
                int kq = cc >> 1, half = cc & 1;
                src = (c < 8) ? Ah : Al;
                dst = ((c < 8) ? &sAh[0][0][0] : &sAl[0][0][0]) + kq * 1024 + half * 512;
                gofs = (long)(m0 + half * 64 + lane) * Kd + k0 + kq * 8;
            } else {
                int cc = c & 3;
                src = (c < 20) ? Bh : Bl;
                dst = ((c < 20) ? &sBh[0][0][0] : &sBl[0][0][0]) + cc * 512;
                gofs = (long)(n0 + lane) * Kd + k0 + cc * 8;
            }
            __builtin_amdgcn_global_load_lds(
                (const __attribute__((address_space(1))) unsigned int*)(src + gofs),
                (__attribute__((address_space(3))) unsigned int*)dst, 16, 0, 0);
        }
        __syncthreads();

        bf16x8 fah[2], fal[2], fbh[4], fbl[4];
        #pragma unroll
        for (int i = 0; i < 2; ++i) {
            fah[i] = *(const bf16x8*)&sAh[quad][mw + i * 16 + mr][0];
            fal[i] = *(const bf16x8*)&sAl[quad][mw + i * 16 + mr][0];
        }
        #pragma unroll
        for (int j = 0; j < 4; ++j) {
            fbh[j] = *(const bf16x8*)&sBh[quad][j * 16 + mr][0];
            fbl[j] = *(const bf16x8*)&sBl[quad][j * 16 + mr][0];
        }
        #pragma unroll
        for (int i = 0; i < 2; ++i)
            #pragma unroll
            for (int j = 0; j < 4; ++j) {
                acc[i][j] = __builtin_amdgcn_mfma_f32_16x16x32_bf16(fah[i], fbh[j], acc[i][j], 0, 0, 0);
                acc[i][j] = __builtin_amdgcn_mfma_f32_16x16x32_bf16(fah[i], fbl[j], acc[i][j], 0, 0, 0);
                acc[i][j] = __builtin_amdgcn_mfma_f32_16x16x32_bf16(fal[i], fbh[j], acc[i][j], 0, 0, 0);
            }
        __syncthreads();
    }

    #pragma unroll
    for (int i = 0; i < 2; ++i)
        #pragma unroll
        for (int j = 0; j < 4; ++j)
            #pragma unroll
            for (int r = 0; r < 4; ++r) {
                int row = m0 + mw + i * 16 + quad * 4 + r;
                int col = n0 + j * 16 + mr;
                float v = acc[i][j][r];
                if (relu) v = fmaxf(v, 0.f);
                C[(long)row * N + col] = v;
            }
}

// ---------------------------------------------------------------------------
// HEB = bf16(Q) @ MhT[h], batched over heads.  grid (M/128, NH), 256 thr.
// A: Qbf [4096][1024] bf16 (head h cols h*128..).  B: MhT [8][128][128] bf16
// ([n=e][k=f] layout).  Out: HEBbf [4096][1024] bf16.
// ---------------------------------------------------------------------------
__global__ __launch_bounds__(256) void heb_gemm(
    const u16* __restrict__ Qbf, const u16* __restrict__ MhT,
    u16* __restrict__ HEBbf)
{
    __shared__ __align__(16) u16 sA[4][128][8], sB[4][128][8];

    const int tid  = threadIdx.x;
    const int w    = tid >> 6;
    const int lane = tid & 63;
    const int m0   = blockIdx.x * 128;
    const int h    = blockIdx.y;
    const int mw   = w * 32;
    const int mr   = lane & 15, quad = lane >> 4;
    const u16* Bm  = MhT + h * 16384;

    f32x4 acc[2][8] = {};

    for (int k0 = 0; k0 < 128; k0 += 32) {
        #pragma unroll
        for (int u = 0; u < 4; ++u) {
            int c = (w & 1) * 4 + u;          // chunk 0..7 within matrix
            int kq = c >> 1, half = c & 1;
            const u16* src; u16* dst; long gofs;
            if (w < 2) {
                src = Qbf;
                dst = &sA[0][0][0] + kq * 1024 + half * 512;
                gofs = (long)(m0 + half * 64 + lane) * 1024 + h * 128 + k0 + kq * 8;
            } else {
                src = Bm;
                dst = &sB[0][0][0] + kq * 1024 + half * 512;
                gofs = (long)(half * 64 + lane) * 128 + k0 + kq * 8;
            }
            __builtin_amdgcn_global_load_lds(
                (const __attribute__((address_space(1))) unsigned int*)(src + gofs),
                (__attribute__((address_space(3))) unsigned int*)dst, 16, 0, 0);
        }
        __syncthreads();

        bf16x8 fa[2], fb[8];
        #pragma unroll
        for (int i = 0; i < 2; ++i)
            fa[i] = *(const bf16x8*)&sA[quad][mw + i * 16 + mr][0];
        #pragma unroll
        for (int j = 0; j < 8; ++j)
            fb[j] = *(const bf16x8*)&sB[quad][j * 16 + mr][0];
        #pragma unroll
        for (int i = 0; i < 2; ++i)
            #pragma unroll
            for (int j = 0; j < 8; ++j)
                acc[i][j] = __builtin_amdgcn_mfma_f32_16x16x32_bf16(fa[i], fb[j], acc[i][j], 0, 0, 0);
        __syncthreads();
    }

    #pragma unroll
    for (int i = 0; i < 2; ++i)
        #pragma unroll
        for (int j = 0; j < 8; ++j)
            #pragma unroll
            for (int r = 0; r < 4; ++r) {
                int row = m0 + mw + i * 16 + quad * 4 + r;
                int col = h * 128 + j * 16 + mr;
                HEBbf[(long)row * 1024 + col] = f2bf(acc[i][j][r]);
            }
}

// Qbf = bf16(QV cols 0..1023)
__global__ __launch_bounds__(256) void qcvt(const float* __restrict__ QV,
                                            u16* __restrict__ Qbf)
{
    int i4 = (blockIdx.x * 256 + threadIdx.x) * 4;   // over 4M
    int bt = i4 >> 10, j = i4 & 1023;
    float4 v = *(const float4*)&QV[(long)bt * 2048 + j];
    ushort4 o = {f2bf(v.x), f2bf(v.y), f2bf(v.z), f2bf(v.w)};
    *(ushort4*)&Qbf[i4] = o;
}

// ---------------------------------------------------------------------------
// sig chain (QV row stride 2048, Q = cols 0..1023)
// ---------------------------------------------------------------------------
__global__ void sig_part(const float* __restrict__ QV, float* __restrict__ P)
{
    int j  = blockIdx.x * 256 + threadIdx.x;
    int tc = blockIdx.y;
    int b  = blockIdx.z;
    float s = 0.f, s8 = 0.f;
    int t0 = tc * 256;
    for (int t = t0; t < t0 + 256; ++t) {
        float v = QV[((long)(b * T_ + t)) * 2048 + j];
        s += v;
        if ((t & 7) == 0) s8 += v;
    }
    long o = ((long)b * 8 + tc) * 1024 + j;
    P[o * 2]     = s;
    P[o * 2 + 1] = s8;
}

__global__ void sig_fin(const float* __restrict__ P, float* __restrict__ sig)
{
    int j = blockIdx.x * 256 + threadIdx.x;
    int b = blockIdx.y;
    float s = 0.f, s8 = 0.f;
    for (int tc = 0; tc < 8; ++tc) {
        long o = ((long)b * 8 + tc) * 1024 + j;
        s  += P[o * 2];
        s8 += P[o * 2 + 1];
    }
    sig[b * 1024 + j] = s * (1.0f / 2048.0f) + 0.5f * s8 * (1.0f / 256.0f);
}

__global__ void mlp1(const float* __restrict__ sig, const float* __restrict__ w1,
                     const float* __restrict__ b1, float* __restrict__ H)
{
    int o = blockIdx.x * 256 + threadIdx.x;
    int b = blockIdx.y;
    float a = 0.f;
    for (int k = 0; k < 1024; ++k)
        a += sig[b * 1024 + k] * w1[(long)k * 512 + o];
    a += b1[o];
    H[b * 512 + o] = 0.5f * a * (1.0f + erff(a * 0.70710678118f));
}

__global__ void mlp2(const float* __restrict__ H, const float* __restrict__ w2,
                     const float* __restrict__ b2, const float* __restrict__ base,
                     float* __restrict__ metric)
{
    int c = blockIdx.x * 256 + threadIdx.x;
    int b = blockIdx.y;
    float a = 0.f;
    for (int k = 0; k < 512; ++k)
        a += H[b * 512 + k] * w2[(long)k * 1024 + c];
    float mv = base[c] + 0.1f * (a + b2[c]);
    metric[b * 1024 + c] = fmaxf(mv, 0.f) + log1pf(expf(-fabsf(mv)));
}

// MhT[h][e][f] = sum_r U[h][f][r] * V[h][r][e], bf16 out
__global__ void hebbmat(const float* __restrict__ U, const float* __restrict__ Vh,
                        u16* __restrict__ MhT)
{
    int gid = blockIdx.x * 256 + threadIdx.x;
    int h = gid >> 14;
    int rem = gid & 16383;
    int e = rem >> 7;
    int f = rem & 127;
    float a = 0.f;
    #pragma unroll
    for (int r = 0; r < 32; ++r)
        a += U[(h * 128 + f) * 32 + r] * Vh[(h * 32 + r) * 128 + e];
    MhT[(h * 128 + e) * 128 + f] = f2bf(a);
}

// ---------------------------------------------------------------------------
// Context kernel: hebb loop replaced by HEB load; QV merged layout.
// ---------------------------------------------------------------------------
__global__ __launch_bounds__(256) void context_k(
    const float* __restrict__ QV, const float* __restrict__ metric,
    const u16* __restrict__ HEBbf,
    u16* __restrict__ CTh, u16* __restrict__ CTl)
{
    __shared__ float dq[4][64], wv[4][32];
    __shared__ int   wi[4][32];

    const int w    = threadIdx.x >> 6;
    const int lane = threadIdx.x & 63;
    const int gw   = blockIdx.x * 4 + w;
    const int h    = gw & 7;
    const int bt   = gw >> 3;
    const int t    = bt & (T_ - 1);
    const int b    = bt >> 11;

    const long qrow  = (long)bt * 2048 + h * 128;          // Q in QV
    const long ctrow = (long)bt * 1024 + h * 128;          // CT / HEB

    const int e4     = (lane & 31) * 4;
    const int jhalf  = lane >> 5;
    const float4 qv  = *(const float4*)&QV[qrow + e4];
    const float4 mv  = *(const float4*)&metric[(long)(b * NH_ + h) * HD_ + e4];

    #pragma unroll 4
    for (int it = 0; it < 32; ++it) {
        int j = 2 * it + jhalf;
        int r = t - j; if (r < 0) r = 0;
        const float4 kv = *(const float4*)&QV[((long)(b * T_ + r)) * 2048 + h * 128 + e4];
        float dx = kv.x - qv.x;
        float dy = kv.y - qv.y;
        float dz = kv.z - qv.z;
        float de = kv.w - qv.w;
        float s = mv.x * dx * dx + mv.y * dy * dy + mv.z * dz * dz + mv.w * de * de;
        #pragma unroll
        for (int m = 16; m; m >>= 1) s += __shfl_xor(s, m, 64);
        if ((lane & 31) == 0) dq[w][j] = s;
    }

    float q0 = QV[qrow + lane], q1 = QV[qrow + 64 + lane];
    float ss = q0 * q0 + q1 * q1;
    #pragma unroll
    for (int s = 32; s; s >>= 1) ss += __shfl_xor(ss, s, 64);
    const float qn  = sqrtf(ss);
    const float inv = 1.0f / fmaxf(qn, 1e-12f);

    float d = sqrtf(dq[w][lane] + 1e-8f);
    int jj = lane;

    for (int k = 2; k <= 64; k <<= 1) {
        for (int s = k >> 1; s >= 1; s >>= 1) {
            float od = __shfl_xor(d, s, 64);
            int   oj = __shfl_xor(jj, s, 64);
            bool up    = ((lane & k) == 0);
            bool lower = ((lane & s) == 0);
            bool osm   = (od < d) || (od == d && oj < jj);
            if ((lower == up) ? osm : !osm) { d = od; jj = oj; }
        }
    }

    float wexp = (lane < 32) ? expf(-d) : 0.f;
    float tot = wexp;
    #pragma unroll
    for (int s = 32; s; s >>= 1) tot += __shfl_xor(tot, s, 64);
    float wn = wexp / (tot + 1e-8f);
    if (lane < 32) {
        wv[w][lane] = wn;
        int ii = t - jj; if (ii < 0) ii = 0;
        wi[w][lane] = ii;
    }

    float c0 = 0.f, c1 = 0.f;
    #pragma unroll 4
    for (int k = 0; k < 32; ++k) {
        float wk = wv[w][k];
        long vb = ((long)(b * T_ + wi[w][k])) * 2048 + 1024 + h * 128;
        c0 += wk * QV[vb + lane];
        c1 += wk * QV[vb + 64 + lane];
    }

    if (qn > 0.2f) {
        float s = 0.1f * inv;
        c0 += s * bf2f(HEBbf[ctrow + lane]);
        c1 += s * bf2f(HEBbf[ctrow + 64 + lane]);
    }

    u16 hh, ll;
    split1(q0 * c0, hh, ll);
    CTh[ctrow + lane] = hh; CTl[ctrow + lane] = ll;
    split1(q1 * c1, hh, ll);
    CTh[ctrow + 64 + lane] = hh; CTl[ctrow + 64 + lane] = ll;
}

// ---------------------------------------------------------------------------
extern "C" void kernel_launch(void* const* d_in, const int* in_sizes, int n_in,
                              void* d_out, int out_size, void* d_ws, size_t ws_size,
                              hipStream_t stream)
{
    const float* x     = (const float*)d_in[0];
    const float* enc_q = (const float*)d_in[1];
    const float* enc_v = (const float*)d_in[2];
    const float* w1    = (const float*)d_in[3];
    const float* b1    = (const float*)d_in[4];
    const float* w2    = (const float*)d_in[5];
    const float* b2    = (const float*)d_in[6];
    const float* base  = (const float*)d_in[7];
    const float* hU    = (const float*)d_in[8];
    const float* hV    = (const float*)d_in[9];
    const float* dec   = (const float*)d_in[10];
    float* out = (float*)d_out;
    float* ws  = (float*)d_ws;

    // ws (floats), peak 12.75M = 51 MB:
    float* QV  = ws;                        // [0, 8388608) fp32 [4096][2048]
    u16* wTh   = (u16*)(ws + 8388608);      // 2048*1024 u16 (dead after QV gemm)
    u16* wTl   = (u16*)(ws + 9437184);
    u16* CTh   = (u16*)(ws + 8388608);      // 4096*1024 u16 (after wT dead)
    u16* CTl   = (u16*)(ws + 10485760);
    u16* MhT   = (u16*)(ws + 12582912);     // 8*128*128 u16
    float* P   = ws + 12713984;
    float* sg  = ws + 12746752;
    float* Hh  = ws + 12748800;
    float* Me  = ws + 12749824;
    u16* wdTh  = (u16*)ws;                  // QV region, dead after context_k
    u16* wdTl  = (u16*)(ws + 524288);
    // d_out staging: xh/xl live until QV gemm done; Qbf/HEBbf until final gemm
    u16* xh    = (u16*)d_out;               // 4096*1024 u16
    u16* xl    = xh + 4194304;
    u16* Qbf   = (u16*)d_out;               // after xh dead
    u16* HEBbf = (u16*)d_out + 4194304;     // after xl dead

    cvt_split<<<4096, 256, 0, stream>>>(x, xh, xl, 4194304);

    // merged weights: enc_q -> rows 0..1023, enc_v -> rows 1024..2047
    cvt_wT<<<dim3(32, 32), 256, 0, stream>>>(enc_q, wTh, wTl, 1024, 7, 127, 131072L, 128);
    cvt_wT<<<dim3(32, 32), 256, 0, stream>>>(enc_v, wTh + 1048576, wTl + 1048576,
                                             1024, 7, 127, 131072L, 128);
    // QV = relu(x @ [enc_q | enc_v])
    gemm_mfma<<<dim3(32, 32), 256, 0, stream>>>(xh, xl, wTh, wTl, QV, 4096, 2048, 1024, 1);

    qcvt<<<4096, 256, 0, stream>>>(QV, Qbf);

    sig_part<<<dim3(4, 8, 2), 256, 0, stream>>>(QV, P);
    sig_fin <<<dim3(4, 2),    256, 0, stream>>>(P, sg);
    mlp1    <<<dim3(2, 2),    256, 0, stream>>>(sg, w1, b1, Hh);
    mlp2    <<<dim3(4, 2),    256, 0, stream>>>(Hh, w2, b2, base, Me);
    hebbmat <<<512,           256, 0, stream>>>(hU, hV, MhT);
    heb_gemm<<<dim3(32, 8),   256, 0, stream>>>(Qbf, MhT, HEBbf);

    context_k<<<8192, 256, 0, stream>>>(QV, Me, HEBbf, CTh, CTl);

    // out = CT @ decoder
    cvt_wT<<<dim3(32, 32), 256, 0, stream>>>(dec, wdTh, wdTl, 1024, 30, 0x3fffffff, 0L, 1024);
    gemm_mfma<<<dim3(16, 32), 256, 0, stream>>>(CTh, CTl, wdTh, wdTl, out, 4096, 1024, 1024, 0);
}

// Round 5
// 550.184 us; speedup vs baseline: 1.6180x; 1.0216x over previous
//
#include <hip/hip_runtime.h>
#include <math.h>

#define T_ 2048
#define NH_ 8
#define HD_ 128

typedef unsigned short u16;
typedef short bf16x8 __attribute__((ext_vector_type(8)));
typedef float f32x4 __attribute__((ext_vector_type(4)));

__device__ __forceinline__ u16 f2bf(float f)
{
    unsigned u = __float_as_uint(f);
    return (u16)((u + 0x7FFFu + ((u >> 16) & 1u)) >> 16);
}
__device__ __forceinline__ float bf2f(u16 h)
{
    return __uint_as_float(((unsigned)h) << 16);
}
// fp32 -> (hi, lo) bf16 split; a ~= hi + lo, rel err ~2^-17
__device__ __forceinline__ void split1(float f, u16& h, u16& l)
{
    h = f2bf(f);
    l = f2bf(f - bf2f(h));
}

// elementwise split of x: [n] fp32 -> hi/lo bf16
__global__ __launch_bounds__(256) void cvt_split(const float* __restrict__ in,
                                                 u16* __restrict__ hi,
                                                 u16* __restrict__ lo, int n)
{
    int i = (blockIdx.x * 256 + threadIdx.x) * 4;
    if (i >= n) return;
    float4 v = *(const float4*)&in[i];
    u16 h0, l0, h1, l1, h2, l2, h3, l3;
    split1(v.x, h0, l0); split1(v.y, h1, l1);
    split1(v.z, h2, l2); split1(v.w, h3, l3);
    ushort4 hv = {h0, h1, h2, h3}, lv = {l0, l1, l2, l3};
    *(ushort4*)&hi[i] = hv;
    *(ushort4*)&lo[i] = lv;
}

// ---------------------------------------------------------------------------
// Weight convert + transpose: Bw element (k,c) at (c>>cs)*sn + k*sk + (c&cm)
// -> WT_hi/WT_lo [n][Kd] bf16 (k contiguous).  grid (Kd/32, Ncols/32), 256 thr.
// ---------------------------------------------------------------------------
__global__ __launch_bounds__(256) void cvt_wT(const float* __restrict__ Bw,
                                              u16* __restrict__ WTh,
                                              u16* __restrict__ WTl,
                                              int Kd, int cs, int cm, long sn, int sk)
{
    __shared__ u16 tH[32][33], tL[32][33];
    const int tid = threadIdx.x;
    const int tx = tid & 31, ty = tid >> 5;
    const int k0 = blockIdx.x * 32, c0 = blockIdx.y * 32;
    #pragma unroll
    for (int r = 0; r < 4; ++r) {
        int k = k0 + ty * 4 + r;
        int c = c0 + tx;
        float v = Bw[(long)(c >> cs) * sn + (long)k * sk + (c & cm)];
        u16 h, l; split1(v, h, l);
        tH[ty * 4 + r][tx] = h;
        tL[ty * 4 + r][tx] = l;
    }
    __syncthreads();
    #pragma unroll
    for (int r = 0; r < 4; ++r) {
        int n = c0 + ty * 4 + r;
        WTh[(long)n * Kd + k0 + tx] = tH[tx][ty * 4 + r];
        WTl[(long)n * Kd + k0 + tx] = tL[tx][ty * 4 + r];
    }
}

// ---------------------------------------------------------------------------
// Split-bf16 MFMA GEMM: C[M,N] = act((Ah+Al) @ (Bh+Bl))
//   A hi/lo: [M][Kd] bf16 row-major.  B hi/lo: [N][Kd] bf16 (pre-transposed).
// Tile 128x128, BK=32, 256 thr / 4 waves (each 64x64 quadrant).
// 32 KB LDS, 48 MFMA + 16 ds_read_b128 + 8 global_load_lds per wave/K-step.
// Run at >=2 blocks/CU (grid >= 512) for barrier-drain overlap.
// ---------------------------------------------------------------------------
__global__ __launch_bounds__(256) void gemm_mfma(
    const u16* __restrict__ Ah, const u16* __restrict__ Al,
    const u16* __restrict__ Bh, const u16* __restrict__ Bl,
    float* __restrict__ C, int M, int N, int Kd, int relu)
{
    __shared__ __align__(16) u16 sAh[4][128][8], sAl[4][128][8];
    __shared__ __align__(16) u16 sBh[4][128][8], sBl[4][128][8];

    const int tid  = threadIdx.x;
    const int w    = tid >> 6;
    const int lane = tid & 63;
    const int m0   = blockIdx.y * 128, n0 = blockIdx.x * 128;
    const int mw   = (w & 1) * 64, nw = (w >> 1) * 64;
    const int mr   = lane & 15, quad = lane >> 4;

    // wave w stages matrix w: 0->Ah, 1->Al, 2->Bh, 3->Bl
    const u16* P = (w == 0) ? Ah : (w == 1) ? Al : (w == 2) ? Bh : Bl;
    u16* D = (w == 0) ? &sAh[0][0][0] : (w == 1) ? &sAl[0][0][0]
           : (w == 2) ? &sBh[0][0][0] : &sBl[0][0][0];
    const int rbase = (w < 2) ? m0 : n0;

    f32x4 acc[4][4] = {};

    for (int k0 = 0; k0 < Kd; k0 += 32) {
        #pragma unroll
        for (int q = 0; q < 8; ++q) {
            int kq = q >> 1, half = q & 1;
            const u16* gp = P + (long)(rbase + half * 64 + lane) * Kd + k0 + kq * 8;
            u16* lp = D + kq * 1024 + half * 512;   // wave-uniform base; HW adds lane*16
            __builtin_amdgcn_global_load_lds(
                (const __attribute__((address_space(1))) unsigned int*)gp,
                (__attribute__((address_space(3))) unsigned int*)lp, 16, 0, 0);
        }
        __syncthreads();

        bf16x8 fah[4], fal[4], fbh[4], fbl[4];
        #pragma unroll
        for (int i = 0; i < 4; ++i) {
            fah[i] = *(const bf16x8*)&sAh[quad][mw + i * 16 + mr][0];
            fal[i] = *(const bf16x8*)&sAl[quad][mw + i * 16 + mr][0];
            fbh[i] = *(const bf16x8*)&sBh[quad][nw + i * 16 + mr][0];
            fbl[i] = *(const bf16x8*)&sBl[quad][nw + i * 16 + mr][0];
        }
        #pragma unroll
        for (int i = 0; i < 4; ++i)
            #pragma unroll
            for (int j = 0; j < 4; ++j) {
                acc[i][j] = __builtin_amdgcn_mfma_f32_16x16x32_bf16(fah[i], fbh[j], acc[i][j], 0, 0, 0);
                acc[i][j] = __builtin_amdgcn_mfma_f32_16x16x32_bf16(fah[i], fbl[j], acc[i][j], 0, 0, 0);
                acc[i][j] = __builtin_amdgcn_mfma_f32_16x16x32_bf16(fal[i], fbh[j], acc[i][j], 0, 0, 0);
            }
        __syncthreads();
    }

    #pragma unroll
    for (int i = 0; i < 4; ++i)
        #pragma unroll
        for (int j = 0; j < 4; ++j)
            #pragma unroll
            for (int r = 0; r < 4; ++r) {
                int row = m0 + mw + i * 16 + quad * 4 + r;
                int col = n0 + nw + j * 16 + mr;
                float v = acc[i][j][r];
                if (relu) v = fmaxf(v, 0.f);
                C[(long)row * N + col] = v;
            }
}

// ---------------------------------------------------------------------------
// HEB = bf16(Q) @ MhT[h], batched over heads.  grid (M/128, NH), 256 thr.
// ---------------------------------------------------------------------------
__global__ __launch_bounds__(256) void heb_gemm(
    const u16* __restrict__ Qbf, const u16* __restrict__ MhT,
    u16* __restrict__ HEBbf)
{
    __shared__ __align__(16) u16 sA[4][128][8], sB[4][128][8];

    const int tid  = threadIdx.x;
    const int w    = tid >> 6;
    const int lane = tid & 63;
    const int m0   = blockIdx.x * 128;
    const int h    = blockIdx.y;
    const int mw   = w * 32;
    const int mr   = lane & 15, quad = lane >> 4;
    const u16* Bm  = MhT + h * 16384;

    f32x4 acc[2][8] = {};

    for (int k0 = 0; k0 < 128; k0 += 32) {
        #pragma unroll
        for (int u = 0; u < 4; ++u) {
            int c = (w & 1) * 4 + u;
            int kq = c >> 1, half = c & 1;
            const u16* src; u16* dst; long gofs;
            if (w < 2) {
                src = Qbf;
                dst = &sA[0][0][0] + kq * 1024 + half * 512;
                gofs = (long)(m0 + half * 64 + lane) * 1024 + h * 128 + k0 + kq * 8;
            } else {
                src = Bm;
                dst = &sB[0][0][0] + kq * 1024 + half * 512;
                gofs = (long)(half * 64 + lane) * 128 + k0 + kq * 8;
            }
            __builtin_amdgcn_global_load_lds(
                (const __attribute__((address_space(1))) unsigned int*)(src + gofs),
                (__attribute__((address_space(3))) unsigned int*)dst, 16, 0, 0);
        }
        __syncthreads();

        bf16x8 fa[2], fb[8];
        #pragma unroll
        for (int i = 0; i < 2; ++i)
            fa[i] = *(const bf16x8*)&sA[quad][mw + i * 16 + mr][0];
        #pragma unroll
        for (int j = 0; j < 8; ++j)
            fb[j] = *(const bf16x8*)&sB[quad][j * 16 + mr][0];
        #pragma unroll
        for (int i = 0; i < 2; ++i)
            #pragma unroll
            for (int j = 0; j < 8; ++j)
                acc[i][j] = __builtin_amdgcn_mfma_f32_16x16x32_bf16(fa[i], fb[j], acc[i][j], 0, 0, 0);
        __syncthreads();
    }

    #pragma unroll
    for (int i = 0; i < 2; ++i)
        #pragma unroll
        for (int j = 0; j < 8; ++j)
            #pragma unroll
            for (int r = 0; r < 4; ++r) {
                int row = m0 + mw + i * 16 + quad * 4 + r;
                int col = h * 128 + j * 16 + mr;
                HEBbf[(long)row * 1024 + col] = f2bf(acc[i][j][r]);
            }
}

// Qbf = bf16(QV cols 0..1023)
__global__ __launch_bounds__(256) void qcvt(const float* __restrict__ QV,
                                            u16* __restrict__ Qbf)
{
    int i4 = (blockIdx.x * 256 + threadIdx.x) * 4;
    int bt = i4 >> 10, j = i4 & 1023;
    float4 v = *(const float4*)&QV[(long)bt * 2048 + j];
    ushort4 o = {f2bf(v.x), f2bf(v.y), f2bf(v.z), f2bf(v.w)};
    *(ushort4*)&Qbf[i4] = o;
}

// ---------------------------------------------------------------------------
// sig chain (QV row stride 2048, Q = cols 0..1023)
// ---------------------------------------------------------------------------
__global__ void sig_part(const float* __restrict__ QV, float* __restrict__ P)
{
    int j  = blockIdx.x * 256 + threadIdx.x;
    int tc = blockIdx.y;
    int b  = blockIdx.z;
    float s = 0.f, s8 = 0.f;
    int t0 = tc * 256;
    for (int t = t0; t < t0 + 256; ++t) {
        float v = QV[((long)(b * T_ + t)) * 2048 + j];
        s += v;
        if ((t & 7) == 0) s8 += v;
    }
    long o = ((long)b * 8 + tc) * 1024 + j;
    P[o * 2]     = s;
    P[o * 2 + 1] = s8;
}

__global__ void sig_fin(const float* __restrict__ P, float* __restrict__ sig)
{
    int j = blockIdx.x * 256 + threadIdx.x;
    int b = blockIdx.y;
    float s = 0.f, s8 = 0.f;
    for (int tc = 0; tc < 8; ++tc) {
        long o = ((long)b * 8 + tc) * 1024 + j;
        s  += P[o * 2];
        s8 += P[o * 2 + 1];
    }
    sig[b * 1024 + j] = s * (1.0f / 2048.0f) + 0.5f * s8 * (1.0f / 256.0f);
}

__global__ void mlp1(const float* __restrict__ sig, const float* __restrict__ w1,
                     const float* __restrict__ b1, float* __restrict__ H)
{
    int o = blockIdx.x * 256 + threadIdx.x;
    int b = blockIdx.y;
    float a = 0.f;
    for (int k = 0; k < 1024; ++k)
        a += sig[b * 1024 + k] * w1[(long)k * 512 + o];
    a += b1[o];
    H[b * 512 + o] = 0.5f * a * (1.0f + erff(a * 0.70710678118f));
}

__global__ void mlp2(const float* __restrict__ H, const float* __restrict__ w2,
                     const float* __restrict__ b2, const float* __restrict__ base,
                     float* __restrict__ metric)
{
    int c = blockIdx.x * 256 + threadIdx.x;
    int b = blockIdx.y;
    float a = 0.f;
    for (int k = 0; k < 512; ++k)
        a += H[b * 512 + k] * w2[(long)k * 1024 + c];
    float mv = base[c] + 0.1f * (a + b2[c]);
    metric[b * 1024 + c] = fmaxf(mv, 0.f) + log1pf(expf(-fabsf(mv)));
}

// MhT[h][e][f] = sum_r U[h][f][r] * V[h][r][e], bf16 out
__global__ void hebbmat(const float* __restrict__ U, const float* __restrict__ Vh,
                        u16* __restrict__ MhT)
{
    int gid = blockIdx.x * 256 + threadIdx.x;
    int h = gid >> 14;
    int rem = gid & 16383;
    int e = rem >> 7;
    int f = rem & 127;
    float a = 0.f;
    #pragma unroll
    for (int r = 0; r < 32; ++r)
        a += U[(h * 128 + f) * 32 + r] * Vh[(h * 32 + r) * 128 + e];
    MhT[(h * 128 + e) * 128 + f] = f2bf(a);
}

// ---------------------------------------------------------------------------
// Context kernel (unchanged from round 4)
// ---------------------------------------------------------------------------
__global__ __launch_bounds__(256) void context_k(
    const float* __restrict__ QV, const float* __restrict__ metric,
    const u16* __restrict__ HEBbf,
    u16* __restrict__ CTh, u16* __restrict__ CTl)
{
    __shared__ float dq[4][64], wv[4][32];
    __shared__ int   wi[4][32];

    const int w    = threadIdx.x >> 6;
    const int lane = threadIdx.x & 63;
    const int gw   = blockIdx.x * 4 + w;
    const int h    = gw & 7;
    const int bt   = gw >> 3;
    const int t    = bt & (T_ - 1);
    const int b    = bt >> 11;

    const long qrow  = (long)bt * 2048 + h * 128;
    const long ctrow = (long)bt * 1024 + h * 128;

    const int e4     = (lane & 31) * 4;
    const int jhalf  = lane >> 5;
    const float4 qv  = *(const float4*)&QV[qrow + e4];
    const float4 mv  = *(const float4*)&metric[(long)(b * NH_ + h) * HD_ + e4];

    #pragma unroll 4
    for (int it = 0; it < 32; ++it) {
        int j = 2 * it + jhalf;
        int r = t - j; if (r < 0) r = 0;
        const float4 kv = *(const float4*)&QV[((long)(b * T_ + r)) * 2048 + h * 128 + e4];
        float dx = kv.x - qv.x;
        float dy = kv.y - qv.y;
        float dz = kv.z - qv.z;
        float de = kv.w - qv.w;
        float s = mv.x * dx * dx + mv.y * dy * dy + mv.z * dz * dz + mv.w * de * de;
        #pragma unroll
        for (int m = 16; m; m >>= 1) s += __shfl_xor(s, m, 64);
        if ((lane & 31) == 0) dq[w][j] = s;
    }

    float q0 = QV[qrow + lane], q1 = QV[qrow + 64 + lane];
    float ss = q0 * q0 + q1 * q1;
    #pragma unroll
    for (int s = 32; s; s >>= 1) ss += __shfl_xor(ss, s, 64);
    const float qn  = sqrtf(ss);
    const float inv = 1.0f / fmaxf(qn, 1e-12f);

    float d = sqrtf(dq[w][lane] + 1e-8f);
    int jj = lane;

    for (int k = 2; k <= 64; k <<= 1) {
        for (int s = k >> 1; s >= 1; s >>= 1) {
            float od = __shfl_xor(d, s, 64);
            int   oj = __shfl_xor(jj, s, 64);
            bool up    = ((lane & k) == 0);
            bool lower = ((lane & s) == 0);
            bool osm   = (od < d) || (od == d && oj < jj);
            if ((lower == up) ? osm : !osm) { d = od; jj = oj; }
        }
    }

    float wexp = (lane < 32) ? expf(-d) : 0.f;
    float tot = wexp;
    #pragma unroll
    for (int s = 32; s; s >>= 1) tot += __shfl_xor(tot, s, 64);
    float wn = wexp / (tot + 1e-8f);
    if (lane < 32) {
        wv[w][lane] = wn;
        int ii = t - jj; if (ii < 0) ii = 0;
        wi[w][lane] = ii;
    }

    float c0 = 0.f, c1 = 0.f;
    #pragma unroll 4
    for (int k = 0; k < 32; ++k) {
        float wk = wv[w][k];
        long vb = ((long)(b * T_ + wi[w][k])) * 2048 + 1024 + h * 128;
        c0 += wk * QV[vb + lane];
        c1 += wk * QV[vb + 64 + lane];
    }

    if (qn > 0.2f) {
        float s = 0.1f * inv;
        c0 += s * bf2f(HEBbf[ctrow + lane]);
        c1 += s * bf2f(HEBbf[ctrow + 64 + lane]);
    }

    u16 hh, ll;
    split1(q0 * c0, hh, ll);
    CTh[ctrow + lane] = hh; CTl[ctrow + lane] = ll;
    split1(q1 * c1, hh, ll);
    CTh[ctrow + 64 + lane] = hh; CTl[ctrow + 64 + lane] = ll;
}

// ---------------------------------------------------------------------------
extern "C" void kernel_launch(void* const* d_in, const int* in_sizes, int n_in,
                              void* d_out, int out_size, void* d_ws, size_t ws_size,
                              hipStream_t stream)
{
    const float* x     = (const float*)d_in[0];
    const float* enc_q = (const float*)d_in[1];
    const float* enc_v = (const float*)d_in[2];
    const float* w1    = (const float*)d_in[3];
    const float* b1    = (const float*)d_in[4];
    const float* w2    = (const float*)d_in[5];
    const float* b2    = (const float*)d_in[6];
    const float* base  = (const float*)d_in[7];
    const float* hU    = (const float*)d_in[8];
    const float* hV    = (const float*)d_in[9];
    const float* dec   = (const float*)d_in[10];
    float* out = (float*)d_out;
    float* ws  = (float*)d_ws;

    // ws (floats), peak 12.75M = 51 MB:
    float* QV  = ws;                        // [0, 8388608) fp32 [4096][2048]
    u16* wTh   = (u16*)(ws + 8388608);      // 2048*1024 u16 (dead after QV gemm)
    u16* wTl   = (u16*)(ws + 9437184);
    u16* CTh   = (u16*)(ws + 8388608);      // 4096*1024 u16 (after wT dead)
    u16* CTl   = (u16*)(ws + 10485760);
    u16* MhT   = (u16*)(ws + 12582912);     // 8*128*128 u16
    float* P   = ws + 12713984;
    float* sg  = ws + 12746752;
    float* Hh  = ws + 12748800;
    float* Me  = ws + 12749824;
    u16* wdTh  = (u16*)ws;                  // QV region, dead after context_k
    u16* wdTl  = (u16*)(ws + 524288);
    u16* xh    = (u16*)d_out;               // staging in d_out
    u16* xl    = xh + 4194304;
    u16* Qbf   = (u16*)d_out;               // after xh dead
    u16* HEBbf = (u16*)d_out + 4194304;     // after xl dead

    cvt_split<<<4096, 256, 0, stream>>>(x, xh, xl, 4194304);

    // merged weights: enc_q -> rows 0..1023, enc_v -> rows 1024..2047
    cvt_wT<<<dim3(32, 32), 256, 0, stream>>>(enc_q, wTh, wTl, 1024, 7, 127, 131072L, 128);
    cvt_wT<<<dim3(32, 32), 256, 0, stream>>>(enc_v, wTh + 1048576, wTl + 1048576,
                                             1024, 7, 127, 131072L, 128);
    // QV = relu(x @ [enc_q | enc_v]) — 128x128 tile, 512 blocks = 2/CU
    gemm_mfma<<<dim3(16, 32), 256, 0, stream>>>(xh, xl, wTh, wTl, QV, 4096, 2048, 1024, 1);

    qcvt<<<4096, 256, 0, stream>>>(QV, Qbf);

    sig_part<<<dim3(4, 8, 2), 256, 0, stream>>>(QV, P);
    sig_fin <<<dim3(4, 2),    256, 0, stream>>>(P, sg);
    mlp1    <<<dim3(2, 2),    256, 0, stream>>>(sg, w1, b1, Hh);
    mlp2    <<<dim3(4, 2),    256, 0, stream>>>(Hh, w2, b2, base, Me);
    hebbmat <<<512,           256, 0, stream>>>(hU, hV, MhT);
    heb_gemm<<<dim3(32, 8),   256, 0, stream>>>(Qbf, MhT, HEBbf);

    context_k<<<8192, 256, 0, stream>>>(QV, Me, HEBbf, CTh, CTl);

    // out = CT @ decoder — 128x128 tile
    cvt_wT<<<dim3(32, 32), 256, 0, stream>>>(dec, wdTh, wdTl, 1024, 30, 0x3fffffff, 0L, 1024);
    gemm_mfma<<<dim3(8, 32), 256, 0, stream>>>(CTh, CTl, wdTh, wdTl, out, 4096, 1024, 1024, 0);
}